// Round 12
// baseline (366.809 us; speedup 1.0000x reference)
//
#include <hip/hip_runtime.h>
#include <stdint.h>

#define DM    2048
#define NSEQ  4096
#define BB    2
#define NH    16
#define HD    128
#define CHK   128
#define NCHK  32            // NSEQ / CHK
#define NBH   (BB*NH)       // 32
#define MTOT  (BB*NSEQ)     // 8192
#define N3    (3*DM)        // 6144

typedef unsigned short u16;
typedef unsigned int   u32;
typedef __attribute__((ext_vector_type(8))) short s16x8;
typedef __attribute__((ext_vector_type(4))) short s16x4;
typedef __attribute__((ext_vector_type(4))) float f32x4;
typedef __attribute__((ext_vector_type(2))) unsigned short u16x2;

__device__ __forceinline__ float b2f(u16 b){ u32 u = ((u32)b) << 16; float f; __builtin_memcpy(&f,&u,4); return f; }
__device__ __forceinline__ u16 f2b(float f){ u32 u; __builtin_memcpy(&u,&f,4); u += 0x7fffu + ((u>>16)&1u); return (u16)(u>>16); }

__device__ __forceinline__ void gload16(const u16* g, u16* l){
  __builtin_amdgcn_global_load_lds((const __attribute__((address_space(1))) void*)g,
                                   (__attribute__((address_space(3))) void*)l, 16, 0, 0);
}

// ---------------------------------------------------------------------------
// f32 -> bf16 bulk convert: x + w_qkv + w_out in ONE launch
// ---------------------------------------------------------------------------
__global__ __launch_bounds__(256) void conv_all(const float* __restrict__ x,
    u16* __restrict__ xb, const float* __restrict__ wq, u16* __restrict__ wqb,
    const float* __restrict__ wo, u16* __restrict__ wob)
{
  const int n1 = MTOT*DM/4;
  const int n2 = N3*DM/4;
  const int n3 = DM*DM/4;
  for (int i = blockIdx.x*blockDim.x + threadIdx.x; i < n1+n2+n3; i += gridDim.x*blockDim.x){
    const float* s; u16* d; int k;
    if (i < n1)          { s = x;  d = xb;  k = i; }
    else if (i < n1+n2)  { s = wq; d = wqb; k = i - n1; }
    else                 { s = wo; d = wob; k = i - n1 - n2; }
    f32x4 v = *(const f32x4*)(s + (size_t)k*4);
    s16x4 o;
    #pragma unroll
    for (int j=0;j<4;j++) o[j] = (short)f2b(v[j]);
    *(s16x4*)(d + (size_t)k*4) = o;
  }
}

// ===========================================================================
// GEMM core: r9/r11 verbatim (proven 3x). BK=64 dbuf, 8 sub-phases / 2
// K-tiles, OPEN-only barriers, pre-OPEN counted vmcnt(4), setprio,
// 3-bit XOR swizzle (0 conflicts).
// ===========================================================================

#define GEMM256_CORE(GA_, GB_)                                                  \
  __shared__ u16 lds[65536];  /* 128 KiB */                                     \
  const int tid  = threadIdx.x;                                                 \
  const int lane = tid & 63;                                                    \
  const int w    = tid >> 6;                                                    \
  const int wm_i = w >> 2, wn_i = w & 3;                                        \
  const int m0 = blockIdx.y << 8;                                               \
  const int n0 = blockIdx.x << 8;                                               \
  const int l15 = lane & 15, lg = lane >> 4, l7 = lane & 7;                     \
  const int c0 = ((lg)     ^ l7) << 3;   /* kk=0 read slot (u16 units) */       \
  const int c1 = ((4 + lg) ^ l7) << 3;   /* kk=1 read slot */                   \
  const int abase = wm_i*8192 + l15*64;                                         \
  const int bbase = 32768 + (wn_i>>1)*8192 + (wn_i&1)*4096 + l15*64;            \
  const int grow = lane >> 3;                                                   \
  const int gcol = ((lane & 7) ^ grow) * 8;                                     \
  const u16* gAl = GA_ + (size_t)(m0 + grow)*DM + gcol;                         \
  const u16* gBl = GB_ + (size_t)(n0 + grow)*DM + gcol;                         \
  auto STG = [&](const u16* gl, int ldsbase, int h, int kt){                    \
    _Pragma("unroll")                                                           \
    for (int j=0;j<2;j++)                                                       \
      gload16(gl + ((size_t)(h*128 + j*64 + w*8))*DM + (size_t)kt*64,           \
              lds + ldsbase + (j*64 + w*8)*64);                                 \
  };                                                                            \
  f32x4 acc[8][4];                                                              \
  _Pragma("unroll")                                                             \
  for (int m=0;m<8;m++)                                                         \
    _Pragma("unroll")                                                           \
    for (int n=0;n<4;n++) acc[m][n] = f32x4{0.f,0.f,0.f,0.f};                   \
  s16x8 bfr[4][2];                                                              \
  /* prologue: buf0 all (kt0) + buf1-B (kt1); drain to 4; rendezvous */         \
  STG(gBl, 32768,             0, 0); STG(gBl, 32768+8192,       1, 0);          \
  STG(gAl, 0,                 0, 0); STG(gAl, 8192,             1, 0);          \
  STG(gBl, 32768+16384,       0, 1); STG(gBl, 32768+16384+8192, 1, 1);          \
  asm volatile("s_waitcnt vmcnt(4)" ::: "memory");                              \
  __builtin_amdgcn_s_barrier();                                                 \
  for (int it=0; it<15; ++it){                                                  \
    const int k1 = 2*it+1, k2 = 2*it+2, k3 = 2*it+3;                            \
    PH(0,0,0,1, STG(gAl, 16384,             0, k1), (void)0);                   \
    PH(0,1,0,1, STG(gAl, 16384+8192,        1, k1), (void)0);                   \
    PH(0,0,4,0, STG(gBl, 32768,             0, k2), (void)0);                   \
    PH(0,1,4,0, STG(gBl, 32768+8192,        1, k2),                             \
            asm volatile("s_waitcnt vmcnt(4)" ::: "memory"));                   \
    PH(1,0,0,1, STG(gAl, 0,                 0, k2), (void)0);                   \
    PH(1,1,0,1, STG(gAl, 8192,              1, k2), (void)0);                   \
    PH(1,0,4,0, STG(gBl, 32768+16384,       0, k3), (void)0);                   \
    PH(1,1,4,0, STG(gBl, 32768+16384+8192,  1, k3),                             \
            asm volatile("s_waitcnt vmcnt(4)" ::: "memory"));                   \
  }                                                                             \
  /* peeled it=15: only buf1-A (kt31) still needs staging */                    \
  PH(0,0,0,1, STG(gAl, 16384,      0, 31), (void)0);                            \
  PH(0,1,0,1, STG(gAl, 16384+8192, 1, 31), (void)0);                            \
  PH(0,0,4,0, (void)0, (void)0);                                                \
  PH(0,1,4,0, (void)0, asm volatile("s_waitcnt vmcnt(0)" ::: "memory"));        \
  PH(1,0,0,1, (void)0, (void)0); PH(1,1,0,1, (void)0, (void)0);                 \
  PH(1,0,4,0, (void)0, (void)0); PH(1,1,4,0, (void)0, (void)0);

// phase: { reads (af x4, optional bf x4 for this kk) ; stage ; [vmcnt] ;
//          OPEN barrier ; setprio ; 16 MFMA (m MB..MB+3, single kk) }
#define PH(D, KK, MB, BFRD, STAGE, VM) do{                                      \
  s16x8 af[4];                                                                  \
  const int cc_ = (KK) ? c1 : c0;                                               \
  if (BFRD){                                                                    \
    _Pragma("unroll")                                                           \
    for (int n=0;n<4;n++)                                                       \
      bfr[n][KK] = *(const s16x8*)(lds + bbase + (D)*16384 + n*1024 + cc_);     \
  }                                                                             \
  _Pragma("unroll")                                                             \
  for (int j=0;j<4;j++)                                                         \
    af[j] = *(const s16x8*)(lds + abase + (D)*16384 + ((MB)+j)*1024 + cc_);     \
  STAGE;                                                                        \
  VM;                                                                           \
  __builtin_amdgcn_s_barrier();                                                 \
  __builtin_amdgcn_s_setprio(1);                                                \
  _Pragma("unroll")                                                             \
  for (int j=0;j<4;j++)                                                         \
    _Pragma("unroll")                                                           \
    for (int n=0;n<4;n++)                                                       \
      acc[(MB)+j][n] = __builtin_amdgcn_mfma_f32_16x16x32_bf16(                 \
          af[j], bfr[n][KK], acc[(MB)+j][n], 0,0,0);                            \
  __builtin_amdgcn_s_setprio(0);                                                \
}while(0)

// ---------------------------------------------------------------------------
// GEMM0: qkv = xb @ wb^T + bias ; scatter bf16 -> Q/K/V (B,H,N,d)
// ---------------------------------------------------------------------------
__global__ __launch_bounds__(512, 2) void gemm_qkv(const u16* __restrict__ Xb,
    const u16* __restrict__ Wb, const float* __restrict__ bias,
    u16* __restrict__ Qb, u16* __restrict__ Kb, u16* __restrict__ Vb)
{
  GEMM256_CORE(Xb, Wb)

  #pragma unroll
  for (int n=0;n<4;n++){
    const int gn = n0 + wn_i*64 + n*16 + l15;
    const float bv = bias[gn];
    const int which = gn >> 11;       // 0=q 1=k 2=v (256-blocks never straddle)
    const int h = (gn >> 7) & 15;
    const int e = gn & 127;
    u16* base_ = (which==0) ? Qb : ((which==1) ? Kb : Vb);
    #pragma unroll
    for (int m=0;m<8;m++){
      #pragma unroll
      for (int r=0;r<4;r++){
        const int gm = m0 + wm_i*128 + m*16 + lg*4 + r;
        const int b  = gm >> 12;
        const int tt = gm & (NSEQ-1);
        base_[(((size_t)(b*NH + h))*NSEQ + tt)*HD + e] = f2b(acc[m][n][r] + bv);
      }
    }
  }
}

// ---------------------------------------------------------------------------
// GEMM1: out = attn @ w_out^T + b_out (f32 out)
// ---------------------------------------------------------------------------
__global__ __launch_bounds__(512, 2) void gemm_out(const u16* __restrict__ Ab,
    const u16* __restrict__ Wb, const float* __restrict__ bias,
    float* __restrict__ Out)
{
  GEMM256_CORE(Ab, Wb)

  #pragma unroll
  for (int n=0;n<4;n++){
    const int gn = n0 + wn_i*64 + n*16 + l15;
    const float bv = bias[gn];
    #pragma unroll
    for (int m=0;m<8;m++){
      #pragma unroll
      for (int r=0;r<4;r++){
        const int gm = m0 + wm_i*128 + m*16 + lg*4 + r;
        Out[(size_t)gm*DM + gn] = acc[m][n][r] + bv;
      }
    }
  }
}

// ---------------------------------------------------------------------------
// chunk_kv: emits U^T (r11, proven):
//   Ut[bh][c][f][d] = sum_t decay_k[t]*K[t][d]*V[t][f]
// ---------------------------------------------------------------------------
__global__ __launch_bounds__(256) void chunk_kv(const u16* __restrict__ Kb,
    const u16* __restrict__ Vb, u16* __restrict__ USb)
{
  __shared__ short Kt[128][152];
  __shared__ short Vt[128][152];
  __shared__ float dkt[128];      // dkt[t] = lam^(127-t)
  const int tid = threadIdx.x;
  const int blk = blockIdx.x;
  const int c  = blk & (NCHK-1);
  const int bh = blk >> 5;
  const int h  = bh & (NH-1);
  const float slope = exp2f(-0.5f*(float)(h+1));

  if (tid < 128) dkt[tid] = expf(-slope*(float)(CHK-1-tid));
  __syncthreads();

  const u16* kg = Kb + ((size_t)bh*NSEQ + (size_t)c*CHK)*HD;
  const u16* vg = Vb + ((size_t)bh*NSEQ + (size_t)c*CHK)*HD;

  const int e0 = (tid & 63) * 2;
  const int tq = tid >> 6;
  #pragma unroll
  for (int it=0; it<4; it++){
    const int tb = it*32 + tq*8;
    s16x8 k0v, k1v, v0v, v1v;
    #pragma unroll
    for (int j=0;j<8;j++){
      const int t = tb + j;
      u16x2 kv = *(const u16x2*)(kg + (size_t)t*HD + e0);
      u16x2 vv = *(const u16x2*)(vg + (size_t)t*HD + e0);
      const float dk = dkt[t];
      k0v[j] = (short)f2b(b2f(kv[0])*dk);
      k1v[j] = (short)f2b(b2f(kv[1])*dk);
      v0v[j] = (short)vv[0];
      v1v[j] = (short)vv[1];
    }
    *(s16x8*)&Kt[e0  ][tb] = k0v;
    *(s16x8*)&Kt[e0+1][tb] = k1v;
    *(s16x8*)&Vt[e0  ][tb] = v0v;
    *(s16x8*)&Vt[e0+1][tb] = v1v;
  }
  __syncthreads();

  const int lane = tid & 63;
  const int l15 = lane & 15, lg = lane >> 4;
  const int w = tid >> 6;
  const int wm = (w >> 1) << 6, wn = (w & 1) << 6;
  f32x4 acc[4][4];
  #pragma unroll
  for (int i=0;i<4;i++)
    #pragma unroll
    for (int j=0;j<4;j++) acc[i][j] = f32x4{0.f,0.f,0.f,0.f};

  #pragma unroll
  for (int ks=0; ks<4; ks++){
    const int kk = ks*32 + lg*8;
    s16x8 af[4], bf[4];
    #pragma unroll
    for (int m=0;m<4;m++) af[m] = *(const s16x8*)&Vt[wm + m*16 + l15][kk];  // f-rows
    #pragma unroll
    for (int n=0;n<4;n++) bf[n] = *(const s16x8*)&Kt[wn + n*16 + l15][kk];  // d-cols
    #pragma unroll
    for (int m=0;m<4;m++)
      #pragma unroll
      for (int n=0;n<4;n++)
        acc[m][n] = __builtin_amdgcn_mfma_f32_16x16x32_bf16(af[m], bf[n], acc[m][n], 0,0,0);
  }

  u16* up = USb + (size_t)blk*(HD*HD);
  #pragma unroll
  for (int m=0;m<4;m++)
    #pragma unroll
    for (int n=0;n<4;n++)
      #pragma unroll
      for (int r=0;r<4;r++){
        const int f = wm + m*16 + lg*4 + r;   // row of U^T
        const int d = wn + n*16 + l15;        // col of U^T
        up[f*HD + d] = f2b(acc[m][n][r]);
      }
}

// ---------------------------------------------------------------------------
// scan_state: elementwise on U^T, in-place U^T -> S^T (r11, proven)
// ---------------------------------------------------------------------------
__global__ __launch_bounds__(256) void scan_state(u16* __restrict__ USb)
{
  const int bh = blockIdx.x >> 3;
  const int rs = blockIdx.x & 7;
  const int tid = threadIdx.x;
  const int h = bh & (NH-1);
  const float slope = exp2f(-0.5f*(float)(h+1));
  const float lamC = expf(-slope*(float)CHK);
  float s[8];
  #pragma unroll
  for (int i=0;i<8;i++) s[i]=0.f;
  u16* base = USb + (size_t)bh*NCHK*HD*HD + rs*2048;
  const int off = tid*8;
  for (int c=0;c<NCHK;c++){
    u16* p = base + (size_t)c*HD*HD + off;
    s16x8 u = *(const s16x8*)p;
    s16x8 wv;
    #pragma unroll
    for (int j=0;j<8;j++) wv[j] = (short)f2b(s[j]);
    *(s16x8*)p = wv;
    #pragma unroll
    for (int j=0;j<8;j++) s[j] = lamC*s[j] + b2f((u16)u[j]);
  }
}

// ---------------------------------------------------------------------------
// attn_chunk (r12): out = decay_q .* (Q @ S_c) + (dmask o (Q K^T)) @ V.
// LDS only Ks + Vt (74 KB -> 2 blocks/CU). Q fragments preloaded to regs
// direct from global (identical indexing to the old Qs reads); S^T fragments
// read direct from global row-major (16B coalesced; r11's U^T made this
// possible). Scores still alias Ks after the post-mm1 barrier (sync order
// unchanged).
// ---------------------------------------------------------------------------
__global__ __launch_bounds__(512, 4) void attn_chunk(
    const u16* __restrict__ Qb, const u16* __restrict__ Kb, const u16* __restrict__ Vb,
    const u16* __restrict__ Sb, u16* __restrict__ ATT)
{
  __shared__ short alds[36864];    // 72 KiB
  __shared__ float qtab[132];      // qtab[d] = lam^d, d in [0,128]
  short* Ks = alds;                // [128][136]  (aliased by scores after mm1)
  short* Vt = alds + 17408;        // [128][152]  transposed [f][s]

  const int tid = threadIdx.x;
  const int blk = blockIdx.x;
  const int c  = blk & (NCHK-1);
  const int bh = blk >> 5;
  const int b  = bh >> 4, h = bh & 15;
  const float slope = exp2f(-0.5f*(float)(h+1));

  if (tid < 129) qtab[tid] = expf(-slope*(float)tid);

  const size_t qoff = ((size_t)bh*NSEQ + (size_t)c*CHK)*HD;
  const u16* sg = Sb + ((size_t)bh*NCHK + c)*HD*HD;

  const int lane = tid & 63;
  const int l15 = lane & 15, lg = lane >> 4;
  const int w = tid >> 6;
  const int wrow = (w >> 1) << 5;
  const int wcol = (w & 1) << 6;

  // preload Q fragments direct from global (16B coalesced within row)
  s16x8 qa[2][4];
  #pragma unroll
  for (int m=0;m<2;m++)
    #pragma unroll
    for (int ks=0;ks<4;ks++)
      qa[m][ks] = *(const s16x8*)(Qb + qoff + (size_t)(wrow + m*16 + l15)*HD + ks*32 + lg*8);

  // stage K natural rows
  #pragma unroll
  for (int i=0;i<4;i++){
    const int lin = i*4096 + tid*8;
    const int r = lin >> 7, e = lin & 127;
    *(s16x8*)&Ks[r*136 + e] = *(const s16x8*)(Kb + qoff + lin);
  }
  // stage V transposed ([s][f] -> [f][s])
  {
    const int f0 = (tid & 63)*2;
    const int tq = tid >> 6;
    const u16* vg = Vb + qoff;
    #pragma unroll
    for (int it=0; it<2; it++){
      const int t0 = it*64 + tq*8;
      s16x8 v0v, v1v;
      #pragma unroll
      for (int j=0;j<8;j++){
        u16x2 v2 = *(const u16x2*)(vg + (size_t)(t0+j)*HD + f0);
        v0v[j]=(short)v2[0]; v1v[j]=(short)v2[1];
      }
      *(s16x8*)&Vt[(f0  )*152 + t0] = v0v;
      *(s16x8*)&Vt[(f0+1)*152 + t0] = v1v;
    }
  }
  __syncthreads();

  f32x4 accs[2][4], acco[2][4];
  #pragma unroll
  for (int m=0;m<2;m++)
    #pragma unroll
    for (int n=0;n<4;n++){ accs[m][n]=f32x4{0.f,0.f,0.f,0.f}; acco[m][n]=f32x4{0.f,0.f,0.f,0.f}; }

  // mm1 (scores = Q K^T) + mm3 (inter = Q @ S^T-cols): kb_ from LDS,
  // sb_ direct from global (L2-resident, 16B loads)
  #pragma unroll
  for (int ks=0; ks<4; ks++){
    const int kk = ks*32 + lg*8;
    s16x8 kb_[4], sb_[4];
    #pragma unroll
    for (int n=0;n<4;n++){
      kb_[n] = *(const s16x8*)&Ks[(wcol + n*16 + l15)*136 + kk];
      sb_[n] = *(const s16x8*)(sg + (size_t)(wcol + n*16 + l15)*HD + kk);
    }
    #pragma unroll
    for (int m=0;m<2;m++)
      #pragma unroll
      for (int n=0;n<4;n++){
        accs[m][n] = __builtin_amdgcn_mfma_f32_16x16x32_bf16(qa[m][ks], kb_[n], accs[m][n], 0,0,0);
        acco[m][n] = __builtin_amdgcn_mfma_f32_16x16x32_bf16(qa[m][ks], sb_[n], acco[m][n], 0,0,0);
      }
  }
  __syncthreads();    // all waves done reading Ks

  #pragma unroll
  for (int m=0;m<2;m++){
    #pragma unroll
    for (int r=0;r<4;r++){
      const int t = wrow + m*16 + lg*4 + r;
      const float dq = qtab[t+1];
      #pragma unroll
      for (int n=0;n<4;n++){
        const int s = wcol + n*16 + l15;
        float v = accs[m][n][r];
        v = (t >= s) ? v*qtab[t-s] : 0.f;
        Ks[t*136 + s] = (short)f2b(v);
        acco[m][n][r] *= dq;
      }
    }
  }
  __syncthreads();    // scores visible

  #pragma unroll
  for (int ks=0; ks<4; ks++){
    const int kk = ks*32 + lg*8;
    s16x8 sa[2], vb_[4];
    #pragma unroll
    for (int m=0;m<2;m++) sa[m] = *(const s16x8*)&Ks[(wrow + m*16 + l15)*136 + kk];
    #pragma unroll
    for (int n=0;n<4;n++) vb_[n] = *(const s16x8*)&Vt[(wcol + n*16 + l15)*152 + kk];
    #pragma unroll
    for (int m=0;m<2;m++)
      #pragma unroll
      for (int n=0;n<4;n++)
        acco[m][n] = __builtin_amdgcn_mfma_f32_16x16x32_bf16(sa[m], vb_[n], acco[m][n], 0,0,0);
  }

  u16* op = ATT + ((size_t)(b*NSEQ + c*CHK))*DM + h*HD;
  #pragma unroll
  for (int m=0;m<2;m++)
    #pragma unroll
    for (int n=0;n<4;n++)
      #pragma unroll
      for (int r=0;r<4;r++){
        const int t = wrow + m*16 + lg*4 + r;
        const int f = wcol + n*16 + l15;
        op[(size_t)t*DM + f] = f2b(acco[m][n][r]);
      }
}

// ---------------------------------------------------------------------------
extern "C" void kernel_launch(void* const* d_in, const int* in_sizes, int n_in,
                              void* d_out, int out_size, void* d_ws, size_t ws_size,
                              hipStream_t stream)
{
  const float* x     = (const float*)d_in[0];
  const float* w_qkv = (const float*)d_in[1];
  const float* b_qkv = (const float*)d_in[2];
  const float* w_out = (const float*)d_in[3];
  const float* b_out = (const float*)d_in[4];
  float* out = (float*)d_out;

  char* ws = (char*)d_ws;
  const size_t SZ = (size_t)MTOT * DM * sizeof(u16);   // 32 MiB
  u16* Qb    = (u16*)(ws);
  u16* Kb    = (u16*)(ws + SZ);
  u16* Vb    = (u16*)(ws + 2*SZ);
  u16* USb   = (u16*)(ws + 3*SZ);      // Wqkvb aliases here (before chunk_kv)
  u16* ATT   = (u16*)(ws + 4*SZ);      // Xb aliases here (before attn_chunk)
  u16* Xb    = ATT;
  u16* Wqkvb = USb;
  u16* Woutb = (u16*)(ws + 5*SZ);      // own 8 MiB slice (DM*DM*2B = 8 MiB)

  conv_all  <<<dim3(2048), 256, 0, stream>>>(x, Xb, w_qkv, Wqkvb, w_out, Woutb);
  gemm_qkv  <<<dim3(N3/256,  MTOT/256), 512, 0, stream>>>(Xb, Wqkvb, b_qkv, Qb, Kb, Vb);
  chunk_kv  <<<dim3(NBH*NCHK),          256, 0, stream>>>(Kb, Vb, USb);
  scan_state<<<dim3(NBH*8),             256, 0, stream>>>(USb);
  attn_chunk<<<dim3(NBH*NCHK),          512, 0, stream>>>(Qb, Kb, Vb, USb, ATT);
  gemm_out  <<<dim3(DM/256,  MTOT/256), 512, 0, stream>>>(ATT, Woutb, b_out, out);
}

// Round 13
// 358.583 us; speedup vs baseline: 1.0229x; 1.0229x over previous
//
#include <hip/hip_runtime.h>
#include <stdint.h>

#define DM    2048
#define NSEQ  4096
#define BB    2
#define NH    16
#define HD    128
#define CHK   128
#define NCHK  32            // NSEQ / CHK
#define NBH   (BB*NH)       // 32
#define MTOT  (BB*NSEQ)     // 8192
#define N3    (3*DM)        // 6144

typedef unsigned short u16;
typedef unsigned int   u32;
typedef __attribute__((ext_vector_type(8))) short s16x8;
typedef __attribute__((ext_vector_type(4))) short s16x4;
typedef __attribute__((ext_vector_type(4))) float f32x4;
typedef __attribute__((ext_vector_type(2))) unsigned short u16x2;

__device__ __forceinline__ float b2f(u16 b){ u32 u = ((u32)b) << 16; float f; __builtin_memcpy(&f,&u,4); return f; }
__device__ __forceinline__ u16 f2b(float f){ u32 u; __builtin_memcpy(&u,&f,4); u += 0x7fffu + ((u>>16)&1u); return (u16)(u>>16); }

__device__ __forceinline__ void gload16(const u16* g, u16* l){
  __builtin_amdgcn_global_load_lds((const __attribute__((address_space(1))) void*)g,
                                   (__attribute__((address_space(3))) void*)l, 16, 0, 0);
}

// ---------------------------------------------------------------------------
// f32 -> bf16 bulk convert: x + w_qkv + w_out in ONE launch
// ---------------------------------------------------------------------------
__global__ __launch_bounds__(256) void conv_all(const float* __restrict__ x,
    u16* __restrict__ xb, const float* __restrict__ wq, u16* __restrict__ wqb,
    const float* __restrict__ wo, u16* __restrict__ wob)
{
  const int n1 = MTOT*DM/4;
  const int n2 = N3*DM/4;
  const int n3 = DM*DM/4;
  for (int i = blockIdx.x*blockDim.x + threadIdx.x; i < n1+n2+n3; i += gridDim.x*blockDim.x){
    const float* s; u16* d; int k;
    if (i < n1)          { s = x;  d = xb;  k = i; }
    else if (i < n1+n2)  { s = wq; d = wqb; k = i - n1; }
    else                 { s = wo; d = wob; k = i - n1 - n2; }
    f32x4 v = *(const f32x4*)(s + (size_t)k*4);
    s16x4 o;
    #pragma unroll
    for (int j=0;j<4;j++) o[j] = (short)f2b(v[j]);
    *(s16x4*)(d + (size_t)k*4) = o;
  }
}

// ===========================================================================
// GEMM core: r9/r11 verbatim (proven 4x). BK=64 dbuf, 8 sub-phases / 2
// K-tiles, OPEN-only barriers, pre-OPEN counted vmcnt(4), setprio,
// 3-bit XOR swizzle (0 conflicts).
// ===========================================================================

#define GEMM256_CORE(GA_, GB_)                                                  \
  __shared__ u16 lds[65536];  /* 128 KiB */                                     \
  const int tid  = threadIdx.x;                                                 \
  const int lane = tid & 63;                                                    \
  const int w    = tid >> 6;                                                    \
  const int wm_i = w >> 2, wn_i = w & 3;                                        \
  const int m0 = blockIdx.y << 8;                                               \
  const int n0 = blockIdx.x << 8;                                               \
  const int l15 = lane & 15, lg = lane >> 4, l7 = lane & 7;                     \
  const int c0 = ((lg)     ^ l7) << 3;   /* kk=0 read slot (u16 units) */       \
  const int c1 = ((4 + lg) ^ l7) << 3;   /* kk=1 read slot */                   \
  const int abase = wm_i*8192 + l15*64;                                         \
  const int bbase = 32768 + (wn_i>>1)*8192 + (wn_i&1)*4096 + l15*64;            \
  const int grow = lane >> 3;                                                   \
  const int gcol = ((lane & 7) ^ grow) * 8;                                     \
  const u16* gAl = GA_ + (size_t)(m0 + grow)*DM + gcol;                         \
  const u16* gBl = GB_ + (size_t)(n0 + grow)*DM + gcol;                         \
  auto STG = [&](const u16* gl, int ldsbase, int h, int kt){                    \
    _Pragma("unroll")                                                           \
    for (int j=0;j<2;j++)                                                       \
      gload16(gl + ((size_t)(h*128 + j*64 + w*8))*DM + (size_t)kt*64,           \
              lds + ldsbase + (j*64 + w*8)*64);                                 \
  };                                                                            \
  f32x4 acc[8][4];                                                              \
  _Pragma("unroll")                                                             \
  for (int m=0;m<8;m++)                                                         \
    _Pragma("unroll")                                                           \
    for (int n=0;n<4;n++) acc[m][n] = f32x4{0.f,0.f,0.f,0.f};                   \
  s16x8 bfr[4][2];                                                              \
  /* prologue: buf0 all (kt0) + buf1-B (kt1); drain to 4; rendezvous */         \
  STG(gBl, 32768,             0, 0); STG(gBl, 32768+8192,       1, 0);          \
  STG(gAl, 0,                 0, 0); STG(gAl, 8192,             1, 0);          \
  STG(gBl, 32768+16384,       0, 1); STG(gBl, 32768+16384+8192, 1, 1);          \
  asm volatile("s_waitcnt vmcnt(4)" ::: "memory");                              \
  __builtin_amdgcn_s_barrier();                                                 \
  for (int it=0; it<15; ++it){                                                  \
    const int k1 = 2*it+1, k2 = 2*it+2, k3 = 2*it+3;                            \
    PH(0,0,0,1, STG(gAl, 16384,             0, k1), (void)0);                   \
    PH(0,1,0,1, STG(gAl, 16384+8192,        1, k1), (void)0);                   \
    PH(0,0,4,0, STG(gBl, 32768,             0, k2), (void)0);                   \
    PH(0,1,4,0, STG(gBl, 32768+8192,        1, k2),                             \
            asm volatile("s_waitcnt vmcnt(4)" ::: "memory"));                   \
    PH(1,0,0,1, STG(gAl, 0,                 0, k2), (void)0);                   \
    PH(1,1,0,1, STG(gAl, 8192,              1, k2), (void)0);                   \
    PH(1,0,4,0, STG(gBl, 32768+16384,       0, k3), (void)0);                   \
    PH(1,1,4,0, STG(gBl, 32768+16384+8192,  1, k3),                             \
            asm volatile("s_waitcnt vmcnt(4)" ::: "memory"));                   \
  }                                                                             \
  /* peeled it=15: only buf1-A (kt31) still needs staging */                    \
  PH(0,0,0,1, STG(gAl, 16384,      0, 31), (void)0);                            \
  PH(0,1,0,1, STG(gAl, 16384+8192, 1, 31), (void)0);                            \
  PH(0,0,4,0, (void)0, (void)0);                                                \
  PH(0,1,4,0, (void)0, asm volatile("s_waitcnt vmcnt(0)" ::: "memory"));        \
  PH(1,0,0,1, (void)0, (void)0); PH(1,1,0,1, (void)0, (void)0);                 \
  PH(1,0,4,0, (void)0, (void)0); PH(1,1,4,0, (void)0, (void)0);

// phase: { reads (af x4, optional bf x4 for this kk) ; stage ; [vmcnt] ;
//          OPEN barrier ; setprio ; 16 MFMA (m MB..MB+3, single kk) }
#define PH(D, KK, MB, BFRD, STAGE, VM) do{                                      \
  s16x8 af[4];                                                                  \
  const int cc_ = (KK) ? c1 : c0;                                               \
  if (BFRD){                                                                    \
    _Pragma("unroll")                                                           \
    for (int n=0;n<4;n++)                                                       \
      bfr[n][KK] = *(const s16x8*)(lds + bbase + (D)*16384 + n*1024 + cc_);     \
  }                                                                             \
  _Pragma("unroll")                                                             \
  for (int j=0;j<4;j++)                                                         \
    af[j] = *(const s16x8*)(lds + abase + (D)*16384 + ((MB)+j)*1024 + cc_);     \
  STAGE;                                                                        \
  VM;                                                                           \
  __builtin_amdgcn_s_barrier();                                                 \
  __builtin_amdgcn_s_setprio(1);                                                \
  _Pragma("unroll")                                                             \
  for (int j=0;j<4;j++)                                                         \
    _Pragma("unroll")                                                           \
    for (int n=0;n<4;n++)                                                       \
      acc[(MB)+j][n] = __builtin_amdgcn_mfma_f32_16x16x32_bf16(                 \
          af[j], bfr[n][KK], acc[(MB)+j][n], 0,0,0);                            \
  __builtin_amdgcn_s_setprio(0);                                                \
}while(0)

// ---------------------------------------------------------------------------
// GEMM0: qkv = xb @ wb^T + bias ; scatter bf16 -> Q/K/V (B,H,N,d)
// ---------------------------------------------------------------------------
__global__ __launch_bounds__(512, 2) void gemm_qkv(const u16* __restrict__ Xb,
    const u16* __restrict__ Wb, const float* __restrict__ bias,
    u16* __restrict__ Qb, u16* __restrict__ Kb, u16* __restrict__ Vb)
{
  GEMM256_CORE(Xb, Wb)

  #pragma unroll
  for (int n=0;n<4;n++){
    const int gn = n0 + wn_i*64 + n*16 + l15;
    const float bv = bias[gn];
    const int which = gn >> 11;       // 0=q 1=k 2=v (256-blocks never straddle)
    const int h = (gn >> 7) & 15;
    const int e = gn & 127;
    u16* base_ = (which==0) ? Qb : ((which==1) ? Kb : Vb);
    #pragma unroll
    for (int m=0;m<8;m++){
      #pragma unroll
      for (int r=0;r<4;r++){
        const int gm = m0 + wm_i*128 + m*16 + lg*4 + r;
        const int b  = gm >> 12;
        const int tt = gm & (NSEQ-1);
        base_[(((size_t)(b*NH + h))*NSEQ + tt)*HD + e] = f2b(acc[m][n][r] + bv);
      }
    }
  }
}

// ---------------------------------------------------------------------------
// GEMM1: out = attn @ w_out^T + b_out (f32 out)
// ---------------------------------------------------------------------------
__global__ __launch_bounds__(512, 2) void gemm_out(const u16* __restrict__ Ab,
    const u16* __restrict__ Wb, const float* __restrict__ bias,
    float* __restrict__ Out)
{
  GEMM256_CORE(Ab, Wb)

  #pragma unroll
  for (int n=0;n<4;n++){
    const int gn = n0 + wn_i*64 + n*16 + l15;
    const float bv = bias[gn];
    #pragma unroll
    for (int m=0;m<8;m++){
      #pragma unroll
      for (int r=0;r<4;r++){
        const int gm = m0 + wm_i*128 + m*16 + lg*4 + r;
        Out[(size_t)gm*DM + gn] = acc[m][n][r] + bv;
      }
    }
  }
}

// ---------------------------------------------------------------------------
// chunk_kv: emits U^T (r11, proven):
//   Ut[bh][c][f][d] = sum_t decay_k[t]*K[t][d]*V[t][f]
// ---------------------------------------------------------------------------
__global__ __launch_bounds__(256) void chunk_kv(const u16* __restrict__ Kb,
    const u16* __restrict__ Vb, u16* __restrict__ USb)
{
  __shared__ short Kt[128][152];
  __shared__ short Vt[128][152];
  __shared__ float dkt[128];      // dkt[t] = lam^(127-t)
  const int tid = threadIdx.x;
  const int blk = blockIdx.x;
  const int c  = blk & (NCHK-1);
  const int bh = blk >> 5;
  const int h  = bh & (NH-1);
  const float slope = exp2f(-0.5f*(float)(h+1));

  if (tid < 128) dkt[tid] = expf(-slope*(float)(CHK-1-tid));
  __syncthreads();

  const u16* kg = Kb + ((size_t)bh*NSEQ + (size_t)c*CHK)*HD;
  const u16* vg = Vb + ((size_t)bh*NSEQ + (size_t)c*CHK)*HD;

  const int e0 = (tid & 63) * 2;
  const int tq = tid >> 6;
  #pragma unroll
  for (int it=0; it<4; it++){
    const int tb = it*32 + tq*8;
    s16x8 k0v, k1v, v0v, v1v;
    #pragma unroll
    for (int j=0;j<8;j++){
      const int t = tb + j;
      u16x2 kv = *(const u16x2*)(kg + (size_t)t*HD + e0);
      u16x2 vv = *(const u16x2*)(vg + (size_t)t*HD + e0);
      const float dk = dkt[t];
      k0v[j] = (short)f2b(b2f(kv[0])*dk);
      k1v[j] = (short)f2b(b2f(kv[1])*dk);
      v0v[j] = (short)vv[0];
      v1v[j] = (short)vv[1];
    }
    *(s16x8*)&Kt[e0  ][tb] = k0v;
    *(s16x8*)&Kt[e0+1][tb] = k1v;
    *(s16x8*)&Vt[e0  ][tb] = v0v;
    *(s16x8*)&Vt[e0+1][tb] = v1v;
  }
  __syncthreads();

  const int lane = tid & 63;
  const int l15 = lane & 15, lg = lane >> 4;
  const int w = tid >> 6;
  const int wm = (w >> 1) << 6, wn = (w & 1) << 6;
  f32x4 acc[4][4];
  #pragma unroll
  for (int i=0;i<4;i++)
    #pragma unroll
    for (int j=0;j<4;j++) acc[i][j] = f32x4{0.f,0.f,0.f,0.f};

  #pragma unroll
  for (int ks=0; ks<4; ks++){
    const int kk = ks*32 + lg*8;
    s16x8 af[4], bf[4];
    #pragma unroll
    for (int m=0;m<4;m++) af[m] = *(const s16x8*)&Vt[wm + m*16 + l15][kk];  // f-rows
    #pragma unroll
    for (int n=0;n<4;n++) bf[n] = *(const s16x8*)&Kt[wn + n*16 + l15][kk];  // d-cols
    #pragma unroll
    for (int m=0;m<4;m++)
      #pragma unroll
      for (int n=0;n<4;n++)
        acc[m][n] = __builtin_amdgcn_mfma_f32_16x16x32_bf16(af[m], bf[n], acc[m][n], 0,0,0);
  }

  u16* up = USb + (size_t)blk*(HD*HD);
  #pragma unroll
  for (int m=0;m<4;m++)
    #pragma unroll
    for (int n=0;n<4;n++)
      #pragma unroll
      for (int r=0;r<4;r++){
        const int f = wm + m*16 + lg*4 + r;   // row of U^T
        const int d = wn + n*16 + l15;        // col of U^T
        up[f*HD + d] = f2b(acc[m][n][r]);
      }
}

// ---------------------------------------------------------------------------
// scan_state: elementwise on U^T, in-place U^T -> S^T (r11, proven)
// ---------------------------------------------------------------------------
__global__ __launch_bounds__(256) void scan_state(u16* __restrict__ USb)
{
  const int bh = blockIdx.x >> 3;
  const int rs = blockIdx.x & 7;
  const int tid = threadIdx.x;
  const int h = bh & (NH-1);
  const float slope = exp2f(-0.5f*(float)(h+1));
  const float lamC = expf(-slope*(float)CHK);
  float s[8];
  #pragma unroll
  for (int i=0;i<8;i++) s[i]=0.f;
  u16* base = USb + (size_t)bh*NCHK*HD*HD + rs*2048;
  const int off = tid*8;
  for (int c=0;c<NCHK;c++){
    u16* p = base + (size_t)c*HD*HD + off;
    s16x8 u = *(const s16x8*)p;
    s16x8 wv;
    #pragma unroll
    for (int j=0;j<8;j++) wv[j] = (short)f2b(s[j]);
    *(s16x8*)p = wv;
    #pragma unroll
    for (int j=0;j<8;j++) s[j] = lamC*s[j] + b2f((u16)u[j]);
  }
}

// ---------------------------------------------------------------------------
// attn_chunk (r11, proven): out = decay_q.*(Q @ S_c) + (dmask o (Q K^T)) @ V
// S^T read row-major (coalesced) into St[128][136] — no transpose gather.
// ---------------------------------------------------------------------------
__global__ __launch_bounds__(512) void attn_chunk(
    const u16* __restrict__ Qb, const u16* __restrict__ Kb, const u16* __restrict__ Vb,
    const u16* __restrict__ Sb, u16* __restrict__ ATT)
{
  __shared__ short alds[73728];    // 144 KiB
  __shared__ float qtab[132];      // qtab[d] = lam^d, d in [0,128]
  short* Qs = alds;                // [128][136]
  short* Ks = alds + 17408;        // [128][136]  (aliased by scores after mm1)
  short* Vt = alds + 34816;        // [128][152]  transposed [f][s]
  short* St = alds + 54272;        // [128][136]  S^T rows = e (out-feature)

  const int tid = threadIdx.x;
  const int blk = blockIdx.x;
  const int c  = blk & (NCHK-1);
  const int bh = blk >> 5;
  const int b  = bh >> 4, h = bh & 15;
  const float slope = exp2f(-0.5f*(float)(h+1));

  if (tid < 129) qtab[tid] = expf(-slope*(float)tid);

  const size_t qoff = ((size_t)bh*NSEQ + (size_t)c*CHK)*HD;
  const u16* sg = Sb + ((size_t)bh*NCHK + c)*HD*HD;

  #pragma unroll
  for (int i=0;i<4;i++){
    const int lin = i*4096 + tid*8;
    const int r = lin >> 7, e = lin & 127;
    *(s16x8*)&Qs[r*136 + e] = *(const s16x8*)(Qb + qoff + lin);
    *(s16x8*)&Ks[r*136 + e] = *(const s16x8*)(Kb + qoff + lin);
    *(s16x8*)&St[r*136 + e] = *(const s16x8*)(sg + lin);
  }
  {
    const int f0 = (tid & 63)*2;
    const int tq = tid >> 6;
    const u16* vg = Vb + qoff;
    #pragma unroll
    for (int it=0; it<2; it++){
      const int t0 = it*64 + tq*8;
      s16x8 v0v, v1v;
      #pragma unroll
      for (int j=0;j<8;j++){
        u16x2 v2 = *(const u16x2*)(vg + (size_t)(t0+j)*HD + f0);
        v0v[j]=(short)v2[0]; v1v[j]=(short)v2[1];
      }
      *(s16x8*)&Vt[(f0  )*152 + t0] = v0v;
      *(s16x8*)&Vt[(f0+1)*152 + t0] = v1v;
    }
  }
  __syncthreads();

  const int lane = tid & 63;
  const int l15 = lane & 15, lg = lane >> 4;
  const int w = tid >> 6;
  const int wrow = (w >> 1) << 5;
  const int wcol = (w & 1) << 6;

  f32x4 accs[2][4], acco[2][4];
  #pragma unroll
  for (int m=0;m<2;m++)
    #pragma unroll
    for (int n=0;n<4;n++){ accs[m][n]=f32x4{0.f,0.f,0.f,0.f}; acco[m][n]=f32x4{0.f,0.f,0.f,0.f}; }

  #pragma unroll
  for (int ks=0; ks<4; ks++){
    const int kk = ks*32 + lg*8;
    s16x8 qa[2], kb_[4], sb_[4];
    #pragma unroll
    for (int m=0;m<2;m++) qa[m] = *(const s16x8*)&Qs[(wrow + m*16 + l15)*136 + kk];
    #pragma unroll
    for (int n=0;n<4;n++){
      kb_[n] = *(const s16x8*)&Ks[(wcol + n*16 + l15)*136 + kk];
      sb_[n] = *(const s16x8*)&St[(wcol + n*16 + l15)*136 + kk];
    }
    #pragma unroll
    for (int m=0;m<2;m++)
      #pragma unroll
      for (int n=0;n<4;n++){
        accs[m][n] = __builtin_amdgcn_mfma_f32_16x16x32_bf16(qa[m], kb_[n], accs[m][n], 0,0,0);
        acco[m][n] = __builtin_amdgcn_mfma_f32_16x16x32_bf16(qa[m], sb_[n], acco[m][n], 0,0,0);
      }
  }
  __syncthreads();

  #pragma unroll
  for (int m=0;m<2;m++){
    #pragma unroll
    for (int r=0;r<4;r++){
      const int t = wrow + m*16 + lg*4 + r;
      const float dq = qtab[t+1];
      #pragma unroll
      for (int n=0;n<4;n++){
        const int s = wcol + n*16 + l15;
        float v = accs[m][n][r];
        v = (t >= s) ? v*qtab[t-s] : 0.f;
        Ks[t*136 + s] = (short)f2b(v);
        acco[m][n][r] *= dq;
      }
    }
  }
  __syncthreads();

  #pragma unroll
  for (int ks=0; ks<4; ks++){
    const int kk = ks*32 + lg*8;
    s16x8 sa[2], vb_[4];
    #pragma unroll
    for (int m=0;m<2;m++) sa[m] = *(const s16x8*)&Ks[(wrow + m*16 + l15)*136 + kk];
    #pragma unroll
    for (int n=0;n<4;n++) vb_[n] = *(const s16x8*)&Vt[(wcol + n*16 + l15)*152 + kk];
    #pragma unroll
    for (int m=0;m<2;m++)
      #pragma unroll
      for (int n=0;n<4;n++)
        acco[m][n] = __builtin_amdgcn_mfma_f32_16x16x32_bf16(sa[m], vb_[n], acco[m][n], 0,0,0);
  }

  u16* op = ATT + ((size_t)(b*NSEQ + c*CHK))*DM + h*HD;
  #pragma unroll
  for (int m=0;m<2;m++)
    #pragma unroll
    for (int n=0;n<4;n++)
      #pragma unroll
      for (int r=0;r<4;r++){
        const int t = wrow + m*16 + lg*4 + r;
        const int f = wcol + n*16 + l15;
        op[(size_t)t*DM + f] = f2b(acco[m][n][r]);
      }
}

// ---------------------------------------------------------------------------
extern "C" void kernel_launch(void* const* d_in, const int* in_sizes, int n_in,
                              void* d_out, int out_size, void* d_ws, size_t ws_size,
                              hipStream_t stream)
{
  const float* x     = (const float*)d_in[0];
  const float* w_qkv = (const float*)d_in[1];
  const float* b_qkv = (const float*)d_in[2];
  const float* w_out = (const float*)d_in[3];
  const float* b_out = (const float*)d_in[4];
  float* out = (float*)d_out;

  char* ws = (char*)d_ws;
  const size_t SZ = (size_t)MTOT * DM * sizeof(u16);   // 32 MiB
  u16* Qb    = (u16*)(ws);
  u16* Kb    = (u16*)(ws + SZ);
  u16* Vb    = (u16*)(ws + 2*SZ);
  u16* USb   = (u16*)(ws + 3*SZ);      // Wqkvb aliases here (before chunk_kv)
  u16* ATT   = (u16*)(ws + 4*SZ);      // Xb aliases here (before attn_chunk)
  u16* Xb    = ATT;
  u16* Wqkvb = USb;
  u16* Woutb = (u16*)(ws + 5*SZ);      // own 8 MiB slice

  conv_all  <<<dim3(2048), 256, 0, stream>>>(x, Xb, w_qkv, Wqkvb, w_out, Woutb);
  gemm_qkv  <<<dim3(N3/256,  MTOT/256), 512, 0, stream>>>(Xb, Wqkvb, b_qkv, Qb, Kb, Vb);
  chunk_kv  <<<dim3(NBH*NCHK),          256, 0, stream>>>(Kb, Vb, USb);
  scan_state<<<dim3(NBH*8),             256, 0, stream>>>(USb);
  attn_chunk<<<dim3(NBH*NCHK),          512, 0, stream>>>(Qb, Kb, Vb, USb, ATT);
  gemm_out  <<<dim3(DM/256,  MTOT/256), 512, 0, stream>>>(ATT, Woutb, b_out, out);
}